// Round 1
// baseline (979.515 us; speedup 1.0000x reference)
//
#include <hip/hip_runtime.h>
#include <hip/hip_bf16.h>

typedef unsigned short u16;
typedef __attribute__((ext_vector_type(8))) short bf16x8;
typedef __attribute__((ext_vector_type(4))) float f32x4;

static __device__ __forceinline__ u16 f2bf(float f) {
    union { float f; unsigned u; } cv; cv.f = f;
    unsigned u = cv.u;
    unsigned r = u + 0x7FFF + ((u >> 16) & 1);   // round-to-nearest-even
    return (u16)(r >> 16);
}
static __device__ __forceinline__ float bf2f(u16 b) {
    union { unsigned u; float f; } cv; cv.u = ((unsigned)b) << 16;
    return cv.f;
}
static __device__ __forceinline__ float sigmoidf_(float x) {
    return 1.0f / (1.0f + __expf(-x));
}

// ---------------------------------------------------------------------------
// Fuse Wf = wv @ wo (bf16, stored transposed [j][i]) and bfv = bv@wo + bo.
// wv,wo are [256,256] row-major f32.
__global__ __launch_bounds__(256) void fuse_wvwo(
    const float* __restrict__ wv, const float* __restrict__ wo,
    const float* __restrict__ bv, const float* __restrict__ bo,
    u16* __restrict__ WfT, float* __restrict__ bfv)
{
    int j = blockIdx.x;       // output col of Wf
    int i = threadIdx.x;      // output row of Wf
    float s = 0.f;
    for (int k = 0; k < 256; ++k) s += wv[i * 256 + k] * wo[k * 256 + j];
    WfT[j * 256 + i] = f2bf(s);
    if (i == 0) {
        float t = bo[j];
        for (int k = 0; k < 256; ++k) t += bv[k] * wo[k * 256 + j];
        bfv[j] = t;
    }
}

// dst[n*K + k] = bf16(src[k*N + n])   (transpose-convert a [K,N] f32 weight)
__global__ __launch_bounds__(256) void transpose_bf(
    const float* __restrict__ src, u16* __restrict__ dst, int K, int N)
{
    long i = (long)blockIdx.x * 256 + threadIdx.x;
    if (i >= (long)K * N) return;
    int n = (int)(i / K), k = (int)(i % K);
    dst[i] = f2bf(src[(long)k * N + n]);
}

// ---------------------------------------------------------------------------
// Action encoder + LayerNorm -> kv_in (bf16).  8 positions per block.
__global__ __launch_bounds__(256) void ae_ln_kernel(
    const float* __restrict__ action,
    const float* __restrict__ w1, const float* __restrict__ b1,
    const float* __restrict__ w2, const float* __restrict__ b2,
    const float* __restrict__ g, const float* __restrict__ be,
    u16* __restrict__ kvbf)
{
    __shared__ float h1[8][128];
    __shared__ float rbuf[2][4];
    int tid = threadIdx.x;
    long base = (long)blockIdx.x * 8;

    for (int i = tid; i < 1024; i += 256) {
        int p = i >> 7, k = i & 127;
        float a0 = action[(base + p) * 2];
        float a1 = action[(base + p) * 2 + 1];
        float v = a0 * w1[k] + a1 * w1[128 + k] + b1[k];
        h1[p][k] = v > 0.f ? v : 0.f;
    }
    __syncthreads();

    int j = tid;
    float acc[8];
#pragma unroll
    for (int p = 0; p < 8; ++p) acc[p] = b2[j];
    for (int k = 0; k < 128; ++k) {
        float w = w2[k * 256 + j];
#pragma unroll
        for (int p = 0; p < 8; ++p) acc[p] += h1[p][k] * w;
    }

    float gj = g[j], bj = be[j];
    for (int p = 0; p < 8; ++p) {
        float s = acc[p], ss = acc[p] * acc[p];
#pragma unroll
        for (int o = 32; o > 0; o >>= 1) { s += __shfl_xor(s, o); ss += __shfl_xor(ss, o); }
        if ((tid & 63) == 0) { rbuf[0][tid >> 6] = s; rbuf[1][tid >> 6] = ss; }
        __syncthreads();
        float S  = rbuf[0][0] + rbuf[0][1] + rbuf[0][2] + rbuf[0][3];
        float SS = rbuf[1][0] + rbuf[1][1] + rbuf[1][2] + rbuf[1][3];
        float m = S * (1.f / 256.f);
        float var = SS * (1.f / 256.f) - m * m;
        float rs = rsqrtf(var + 1e-5f);
        kvbf[(base + p) * 256 + j] = f2bf((acc[p] - m) * rs * gj + bj);
        __syncthreads();
    }
}

// ---------------------------------------------------------------------------
// Generic 64x64-tile bf16 GEMM:  C = A[M,K] @ BT[N,K]^T  (+bias[col]) (+modes)
// MODE 0: out_bf = bf16(resid + acc + bias)          (x = state + attended)
// MODE 1: out_bf = bf16(acc + bias)                  (gi)
// MODE 2: outF   = acc + bias; duplicate last-t row  (states -> d_out)
template <int MODE>
__global__ __launch_bounds__(256) void gemm64(
    const u16* __restrict__ A, const u16* __restrict__ BT,
    const float* __restrict__ bias, const float* __restrict__ resid,
    u16* __restrict__ outBf, float* __restrict__ outF,
    int N, int K)
{
    __shared__ u16 lA[64][40];
    __shared__ u16 lB[64][40];
    int tid = threadIdx.x;
    int bm = blockIdx.x * 64, bn = blockIdx.y * 64;
    int srow = tid >> 2, sch = (tid & 3) * 8;

    f32x4 acc[2][2] = {};
    int w = tid >> 6, l = tid & 63;
    int wr = (w >> 1) * 32, wc = (w & 1) * 32;
    int fr = l & 15, fk = (l >> 4) * 8;

    for (int k0 = 0; k0 < K; k0 += 32) {
        *(uint4*)&lA[srow][sch] = *(const uint4*)&A[(long)(bm + srow) * K + k0 + sch];
        *(uint4*)&lB[srow][sch] = *(const uint4*)&BT[(long)(bn + srow) * K + k0 + sch];
        __syncthreads();
        bf16x8 a0 = *(bf16x8*)&lA[wr + fr][fk];
        bf16x8 a1 = *(bf16x8*)&lA[wr + 16 + fr][fk];
        bf16x8 b0 = *(bf16x8*)&lB[wc + fr][fk];
        bf16x8 b1 = *(bf16x8*)&lB[wc + 16 + fr][fk];
        acc[0][0] = __builtin_amdgcn_mfma_f32_16x16x32_bf16(a0, b0, acc[0][0], 0, 0, 0);
        acc[0][1] = __builtin_amdgcn_mfma_f32_16x16x32_bf16(a0, b1, acc[0][1], 0, 0, 0);
        acc[1][0] = __builtin_amdgcn_mfma_f32_16x16x32_bf16(a1, b0, acc[1][0], 0, 0, 0);
        acc[1][1] = __builtin_amdgcn_mfma_f32_16x16x32_bf16(a1, b1, acc[1][1], 0, 0, 0);
        __syncthreads();
    }

#pragma unroll
    for (int mi = 0; mi < 2; ++mi)
#pragma unroll
        for (int ni = 0; ni < 2; ++ni) {
            int c = bn + wc + ni * 16 + fr;
            float bz = bias[c];
#pragma unroll
            for (int reg = 0; reg < 4; ++reg) {
                int r = bm + wr + mi * 16 + (l >> 4) * 4 + reg;
                float v = acc[mi][ni][reg] + bz;
                if constexpr (MODE == 0) {
                    v += resid[(long)r * N + c];
                    outBf[(long)r * N + c] = f2bf(v);
                } else if constexpr (MODE == 1) {
                    outBf[(long)r * N + c] = f2bf(v);
                } else {
                    outF[(long)r * N + c] = v;
                    if ((r & 511) == 511) outF[8388608 + (long)(r >> 9) * N + c] = v;
                }
            }
        }
}

// ---------------------------------------------------------------------------
// One GRU step (scan index = step over B).  gh = h@whh for 3 gates fused with
// gate math.  Block tile: 32 t-rows x 64 cols (of 512); 4 waves split cols.
__global__ __launch_bounds__(256) void gru_step(
    const u16* __restrict__ hprev_bf, const float* __restrict__ hprev_f,
    const u16* __restrict__ whhT, const float* __restrict__ bhh,
    const u16* __restrict__ gi_bf,
    float* __restrict__ hnext_f, u16* __restrict__ hnext_bf,
    u16* __restrict__ out_bf, int step)
{
    __shared__ u16 lA[32][40];
    __shared__ u16 lB[192][40];
    int tid = threadIdx.x;
    int tbase = blockIdx.x * 32, cbase = blockIdx.y * 64;

    f32x4 acc[3][2] = {};
    int w = tid >> 6, l = tid & 63;
    int fr = l & 15, fk = (l >> 4) * 8;

    for (int k0 = 0; k0 < 512; k0 += 32) {
        if (tid < 128) {
            int r = tid >> 2, ch = (tid & 3) * 8;
            *(uint4*)&lA[r][ch] = *(const uint4*)&hprev_bf[(long)(tbase + r) * 512 + k0 + ch];
        }
#pragma unroll
        for (int ii = 0; ii < 3; ++ii) {
            int idx = tid + ii * 256;
            int r = idx >> 2, ch = (idx & 3) * 8;
            int gate = r >> 6, cc = r & 63;
            *(uint4*)&lB[r][ch] =
                *(const uint4*)&whhT[(long)(gate * 512 + cbase + cc) * 512 + k0 + ch];
        }
        __syncthreads();
        bf16x8 a0 = *(bf16x8*)&lA[fr][fk];
        bf16x8 a1 = *(bf16x8*)&lA[16 + fr][fk];
#pragma unroll
        for (int gate = 0; gate < 3; ++gate) {
            bf16x8 bb = *(bf16x8*)&lB[gate * 64 + w * 16 + fr][fk];
            acc[gate][0] = __builtin_amdgcn_mfma_f32_16x16x32_bf16(a0, bb, acc[gate][0], 0, 0, 0);
            acc[gate][1] = __builtin_amdgcn_mfma_f32_16x16x32_bf16(a1, bb, acc[gate][1], 0, 0, 0);
        }
        __syncthreads();
    }

    int col = cbase + w * 16 + fr;
    float bhr = bhh[col], bhz = bhh[512 + col], bhn = bhh[1024 + col];
#pragma unroll
    for (int mi = 0; mi < 2; ++mi)
#pragma unroll
        for (int reg = 0; reg < 4; ++reg) {
            int t = tbase + mi * 16 + (l >> 4) * 4 + reg;
            long gbase = ((long)(step * 512 + t)) * 1536;
            float ghr = acc[0][mi][reg] + bhr;
            float ghz = acc[1][mi][reg] + bhz;
            float ghn = acc[2][mi][reg] + bhn;
            float gr = bf2f(gi_bf[gbase + col]);
            float gz = bf2f(gi_bf[gbase + 512 + col]);
            float gn = bf2f(gi_bf[gbase + 1024 + col]);
            float rg = sigmoidf_(gr + ghr);
            float zg = sigmoidf_(gz + ghz);
            float ng = tanhf(gn + rg * ghn);
            float hp = hprev_f[(long)t * 512 + col];
            float hn = (1.f - zg) * ng + zg * hp;
            hnext_f[(long)t * 512 + col] = hn;
            u16 hb = f2bf(hn);
            hnext_bf[(long)t * 512 + col] = hb;
            out_bf[((long)(step * 512 + t)) * 512 + col] = hb;
        }
}

// ---------------------------------------------------------------------------
extern "C" void kernel_launch(void* const* d_in, const int* in_sizes, int n_in,
                              void* d_out, int out_size, void* d_ws, size_t ws_size,
                              hipStream_t stream)
{
    const float* state   = (const float*)d_in[0];
    const float* action  = (const float*)d_in[1];
    const float* ae_w1   = (const float*)d_in[2];
    const float* ae_b1   = (const float*)d_in[3];
    const float* ae_w2   = (const float*)d_in[4];
    const float* ae_b2   = (const float*)d_in[5];
    const float* ln2_g   = (const float*)d_in[8];
    const float* ln2_b   = (const float*)d_in[9];
    const float* wv      = (const float*)d_in[14];
    const float* bv      = (const float*)d_in[15];
    const float* wo      = (const float*)d_in[16];
    const float* bo      = (const float*)d_in[17];
    const float* gru_wih = (const float*)d_in[18];
    const float* gru_bih = (const float*)d_in[19];
    const float* gru_whh = (const float*)d_in[20];
    const float* gru_bhh = (const float*)d_in[21];
    const float* mlp_w   = (const float*)d_in[22];
    const float* mlp_b   = (const float*)d_in[23];

    char* ws = (char*)d_ws;
    size_t off = 0;
    auto carve = [&](size_t bytes) -> char* {
        char* p = ws + off; off = (off + bytes + 255) & ~(size_t)255; return p;
    };
    u16*   kv_bf  = (u16*)carve(32768ull * 256 * 2);
    u16*   x_bf   = (u16*)carve(32768ull * 256 * 2);
    u16*   gi_bf  = (u16*)carve(32768ull * 1536 * 2);
    u16*   out_bf = (u16*)carve(32768ull * 512 * 2);
    u16*   WfT    = (u16*)carve(256 * 256 * 2);
    float* bfv    = (float*)carve(256 * 4);
    u16*   wihT   = (u16*)carve(1536 * 256 * 2);
    u16*   whhT   = (u16*)carve(1536 * 512 * 2);
    u16*   mlpT   = (u16*)carve(256 * 512 * 2);
    float* h_f0   = (float*)carve(512 * 512 * 4);
    float* h_f1   = (float*)carve(512 * 512 * 4);
    u16*   h_b0   = (u16*)carve(512 * 512 * 2);
    u16*   h_b1   = (u16*)carve(512 * 512 * 2);
    float* h_f[2] = { h_f0, h_f1 };
    u16*   h_b[2] = { h_b0, h_b1 };

    hipMemsetAsync(h_f[0], 0, 512 * 512 * 4, stream);
    hipMemsetAsync(h_b[0], 0, 512 * 512 * 2, stream);

    fuse_wvwo<<<256, 256, 0, stream>>>(wv, wo, bv, bo, WfT, bfv);
    transpose_bf<<<1536, 256, 0, stream>>>(gru_wih, wihT, 256, 1536);
    transpose_bf<<<3072, 256, 0, stream>>>(gru_whh, whhT, 512, 1536);
    transpose_bf<<<512, 256, 0, stream>>>(mlp_w, mlpT, 512, 256);

    ae_ln_kernel<<<4096, 256, 0, stream>>>(action, ae_w1, ae_b1, ae_w2, ae_b2,
                                           ln2_g, ln2_b, kv_bf);

    // x = state + kv_in @ Wf + bfv   (bf16 out)
    gemm64<0><<<dim3(512, 4), 256, 0, stream>>>(kv_bf, WfT, bfv, state, x_bf, nullptr, 256, 256);
    // gi = x @ wih + bih             (bf16 out, all B*T rows)
    gemm64<1><<<dim3(512, 24), 256, 0, stream>>>(x_bf, wihT, gru_bih, nullptr, gi_bf, nullptr, 1536, 256);

    for (int b = 0; b < 64; ++b) {
        int cur = b & 1;
        gru_step<<<dim3(16, 8), 256, 0, stream>>>(h_b[cur], h_f[cur], whhT, gru_bhh,
                                                  gi_bf, h_f[cur ^ 1], h_b[cur ^ 1],
                                                  out_bf, b);
    }

    // states = out @ mlp_w + mlp_b   (f32 out + last-row duplicate)
    gemm64<2><<<dim3(512, 4), 256, 0, stream>>>(out_bf, mlpT, mlp_b, nullptr, nullptr,
                                                (float*)d_out, 256, 512);
}